// Round 9
// baseline (581.712 us; speedup 1.0000x reference)
//
#include <hip/hip_runtime.h>
#include <hip/hip_bf16.h>
#include <stdint.h>

#define B_ROWS 16384
#define D_IN   512
#define H_DIM  1024
#define K_TOT  1536
#define NKT    48          // K-tiles of 32

typedef __attribute__((ext_vector_type(8)))  short bf16x8;
typedef __attribute__((ext_vector_type(16))) float f32x16;
typedef __attribute__((ext_vector_type(4)))  float float4v;
typedef __attribute__((ext_vector_type(8)))  unsigned short u16x8;

__device__ __forceinline__ unsigned short f2bf(float f) {
    uint32_t u = __float_as_uint(f);
    u = (u + 0x7FFFu + ((u >> 16) & 1u)) >> 16;   // RNE
    return (unsigned short)u;
}

// ---------------------------------------------------------------------------
// Ag in FRAGMENT-LINEAR TILED order (unchanged):
//   granule g = ((bm*48 + tile)*16 + chunk)*64 + lane   (16 B each)
//   lane l, elem j: row = bm*256 + (chunk>>1)*32 + (l&31)
//                   k   = tile*32 + (chunk&1)*16 + (l>>5)*8 + j
// ---------------------------------------------------------------------------
__global__ void cvt_A(const float* __restrict__ x, const float* __restrict__ h,
                      unsigned short* __restrict__ Ag) {
    int t     = blockIdx.x * blockDim.x + threadIdx.x;
    int lane  = t & 63;
    int chunk = (t >> 6) & 15;
    int rest  = t >> 10;            // bm*48 + tile
    int tile  = rest % 48;
    int bm    = rest / 48;
    int row   = bm * 256 + (chunk >> 1) * 32 + (lane & 31);
    int k     = tile * 32 + (chunk & 1) * 16 + (lane >> 5) * 8;
    const float* src = (k < 512) ? (x + (size_t)row * D_IN + k)
                                 : (h + (size_t)row * H_DIM + (k - 512));
    float4v v0 = *(const float4v*)(src);
    float4v v1 = *(const float4v*)(src + 4);
    u16x8 o;
    o[0] = f2bf(v0[0]); o[1] = f2bf(v0[1]); o[2] = f2bf(v0[2]); o[3] = f2bf(v0[3]);
    o[4] = f2bf(v1[0]); o[5] = f2bf(v1[1]); o[6] = f2bf(v1[2]); o[7] = f2bf(v1[3]);
    *(u16x8*)(Ag + (size_t)t * 8) = o;
}

// ---------------------------------------------------------------------------
// Bg fragment-linear tiled, gate-interleaved cols (granularity 32):
//   col c = (h>>5)*128 + gate*32 + (h&31)
// ---------------------------------------------------------------------------
__global__ void cvt_B(const float* __restrict__ Ui, const float* __restrict__ Uf,
                      const float* __restrict__ Uo, const float* __restrict__ Uc,
                      const float* __restrict__ Wi, const float* __restrict__ Wf,
                      const float* __restrict__ Wo, const float* __restrict__ Wc,
                      unsigned short* __restrict__ Bg) {
    int t     = blockIdx.x * blockDim.x + threadIdx.x;
    int lane  = t & 63;
    int chunk = (t >> 6) & 15;
    int rest  = t >> 10;            // bn*48 + tile
    int tile  = rest % 48;
    int bn    = rest / 48;
    int c     = bn * 256 + (chunk >> 1) * 32 + (lane & 31);
    int g     = (c >> 5) & 3;
    int hcol  = ((c >> 7) << 5) | (c & 31);
    int k     = tile * 32 + (chunk & 1) * 16 + (lane >> 5) * 8;
    const float* up = (g == 0) ? Ui : (g == 1) ? Uf : (g == 2) ? Uo : Uc;
    const float* wp = (g == 0) ? Wi : (g == 1) ? Wf : (g == 2) ? Wo : Wc;
    u16x8 o;
    if (k < 512) {
        const float* s = up + (size_t)k * H_DIM + hcol;
        #pragma unroll
        for (int i = 0; i < 8; ++i) o[i] = f2bf(s[(size_t)i * H_DIM]);
    } else {
        const float* s = wp + (size_t)(k - 512) * H_DIM + hcol;
        #pragma unroll
        for (int i = 0; i < 8; ++i) o[i] = f2bf(s[(size_t)i * H_DIM]);
    }
    *(u16x8*)(Bg + (size_t)t * 8) = o;
}

__global__ void cvt_bias(const float* __restrict__ Uib, const float* __restrict__ Ufb,
                         const float* __restrict__ Uob, const float* __restrict__ Ucb,
                         const float* __restrict__ Wib, const float* __restrict__ Wfb,
                         const float* __restrict__ Wob, const float* __restrict__ Wcb,
                         float* __restrict__ bias) {
    int t = blockIdx.x * blockDim.x + threadIdx.x;
    int g = t >> 10, h = t & 1023;
    const float* ub = (g == 0) ? Uib : (g == 1) ? Ufb : (g == 2) ? Uob : Ucb;
    const float* wb = (g == 0) ? Wib : (g == 1) ? Wfb : (g == 2) ? Wob : Wcb;
    bias[t] = ub[h] + wb[h];
}

// ---- shared macros for the register-direct GEMM and probes ----
#define ALOAD(AF, T) do {                                                           \
    const unsigned short* _a = aB + (size_t)(T) * 8192;                             \
    AF[0] = *(const u16x8*)(_a);        AF[1] = *(const u16x8*)(_a + 512);          \
    AF[2] = *(const u16x8*)(_a + 1024); AF[3] = *(const u16x8*)(_a + 1536);         \
} while (0)

#define BLOAD(BF, T) do {                                                           \
    const unsigned short* _b = bB + (size_t)(T) * 8192;                             \
    BF[0] = *(const u16x8*)(_b);        BF[1] = *(const u16x8*)(_b + 512);          \
    BF[2] = *(const u16x8*)(_b + 1024); BF[3] = *(const u16x8*)(_b + 1536);         \
    BF[4] = *(const u16x8*)(_b + 2048); BF[5] = *(const u16x8*)(_b + 2560);         \
    BF[6] = *(const u16x8*)(_b + 3072); BF[7] = *(const u16x8*)(_b + 3584);         \
} while (0)

#define MFMAS(AF, BF) do {                                                          \
    __builtin_amdgcn_s_setprio(1);                                                  \
    _Pragma("unroll") for (int ks = 0; ks < 2; ++ks)                                \
        _Pragma("unroll") for (int mm = 0; mm < 2; ++mm)                            \
            _Pragma("unroll") for (int nn = 0; nn < 4; ++nn)                        \
                acc[mm][nn] = __builtin_amdgcn_mfma_f32_32x32x16_bf16(              \
                    (bf16x8)AF[mm * 2 + ks], (bf16x8)BF[nn * 2 + ks],               \
                    acc[mm][nn], 0, 0, 0);                                          \
    __builtin_amdgcn_s_setprio(0);                                                  \
} while (0)

// ---------------------------------------------------------------------------
// REAL KERNEL: 256x256 GEMM, mfma_f32_32x32x16_bf16, NO LDS, NO BARRIERS.
// Every wave loads its own A (4 frags) and B (8 frags) per K-32 tile straight
// from fragment-linear Ag/Bg (coalesced dwordx4, L1/L2-served; B is 4x
// wave-redundant but unique-traffic identical). 2-tile register double
// buffer; compiler-managed vmcnt; waves fully independent.
// ---------------------------------------------------------------------------
__global__ __launch_bounds__(512, 2) void lstm_gemm(
        const unsigned short* __restrict__ Ag, const unsigned short* __restrict__ Bg,
        const float* __restrict__ bias, const float* __restrict__ c_old,
        float* __restrict__ out) {
    const int tid = threadIdx.x;
    const int l   = tid & 63;
    const int wv  = tid >> 6;
    const int wm  = wv >> 1;      // 0..3  (64-row slice)
    const int wn  = wv & 1;       // 0..1  (128-col slice)

    // XCD-aware swizzle: per XCD 8bm x 4bn chunks
    const int orig = blockIdx.x;
    const int xcd  = orig & 7;
    const int jj   = orig >> 3;
    const int bn   = (xcd & 3) * 4 + (jj & 3);     // 0..15
    const int bm   = (xcd >> 2) * 32 + (jj >> 2);  // 0..63

    const unsigned short* aB = Ag + ((size_t)bm * 48 * 16 + 4 * wm) * 512 + l * 8;
    const unsigned short* bB = Bg + ((size_t)bn * 48 * 16 + 8 * wn) * 512 + l * 8;

    f32x16 acc[2][4] = {};
    u16x8 a0[4], a1[4], b0[8], b1[8];

    ALOAD(a0, 0); BLOAD(b0, 0);

    #pragma unroll 1
    for (int i = 0; i < 24; ++i) {
        const int t1 = 2 * i + 1;
        int t2 = 2 * i + 2; if (t2 >= NKT) t2 = 0;   // dummy, never consumed
        ALOAD(a1, t1); BLOAD(b1, t1);
        MFMAS(a0, b0);
        ALOAD(a0, t2); BLOAD(b0, t2);
        MFMAS(a1, b1);
    }

    // ---- fused LSTM epilogue: gate = nn (in-lane), hh = (bn*2+wn)*32 + col ----
    const int r31 = l & 31;
    const int h5  = l >> 5;
    const int hh  = (bn * 2 + wn) * 32 + r31;
    const float bi  = bias[hh];
    const float bff = bias[1024 + hh];
    const float bo  = bias[2048 + hh];
    const float bc  = bias[3072 + hh];

    #pragma unroll
    for (int mm = 0; mm < 2; ++mm) {
        const int rb = bm * 256 + wm * 64 + mm * 32 + 4 * h5;
        #pragma unroll
        for (int r = 0; r < 16; ++r) {
            const int row = rb + (r & 3) + 8 * (r >> 2);
            float iv = acc[mm][0][r] + bi;
            float fv = acc[mm][1][r] + bff;
            float ov = acc[mm][2][r] + bo;
            float gv = acc[mm][3][r] + bc;
            float it = 1.f / (1.f + __expf(-iv));
            float ft = 1.f / (1.f + __expf(-fv));
            float ot = 1.f / (1.f + __expf(-ov));
            float gt = 1.f - 2.f / (1.f + __expf(2.f * gv));
            float co = c_old[(size_t)row * H_DIM + hh];
            float cn = it * gt + ft * co;
            float th = 1.f - 2.f / (1.f + __expf(2.f * cn));
            out[(size_t)row * H_DIM + hh] = ot * th;                          // h_new
            out[(size_t)B_ROWS * H_DIM + (size_t)row * H_DIM + hh] = cn;      // c
        }
    }
}

// ---------------------------------------------------------------------------
// PROBE 1: same loop shape, loads removed -> MFMA + loop floor.
// Expect ~83 us (chip MFMA floor), MfmaUtil >= 90%.
// ---------------------------------------------------------------------------
__global__ __launch_bounds__(512, 2) void probe_mfma(
        const unsigned short* __restrict__ Ag, const unsigned short* __restrict__ Bg,
        unsigned short* __restrict__ sink) {
    const int tid = threadIdx.x;
    const int l   = tid & 63;
    const int wv  = tid >> 6;
    const int wm  = wv >> 1;
    const int wn  = wv & 1;
    const int orig = blockIdx.x;
    const int xcd  = orig & 7;
    const int jj   = orig >> 3;
    const int bn   = (xcd & 3) * 4 + (jj & 3);
    const int bm   = (xcd >> 2) * 32 + (jj >> 2);
    const unsigned short* aB = Ag + ((size_t)bm * 48 * 16 + 4 * wm) * 512 + l * 8;
    const unsigned short* bB = Bg + ((size_t)bn * 48 * 16 + 8 * wn) * 512 + l * 8;

    f32x16 acc[2][4] = {};
    u16x8 a0[4], b0[8];
    ALOAD(a0, 0); BLOAD(b0, 0);

    #pragma unroll 1
    for (int i = 0; i < 24; ++i) {
        MFMAS(a0, b0);
        MFMAS(a0, b0);
    }
    // keep acc live: store one row of each accumulator
    float s = 0.f;
    #pragma unroll
    for (int mm = 0; mm < 2; ++mm)
        #pragma unroll
        for (int nn = 0; nn < 4; ++nn) s += acc[mm][nn][0] + acc[mm][nn][15];
    sink[(size_t)(blockIdx.x * 512 + tid)] = f2bf(s);
}

// ---------------------------------------------------------------------------
// PROBE 2: same loads, MFMA removed -> memory-path floor.
// Expect ~100-150 us if BW-bound; >>200 us => latency/issue-bound.
// ---------------------------------------------------------------------------
__global__ __launch_bounds__(512, 2) void probe_mem(
        const unsigned short* __restrict__ Ag, const unsigned short* __restrict__ Bg,
        unsigned short* __restrict__ sink) {
    const int tid = threadIdx.x;
    const int l   = tid & 63;
    const int wv  = tid >> 6;
    const int wm  = wv >> 1;
    const int wn  = wv & 1;
    const int orig = blockIdx.x;
    const int xcd  = orig & 7;
    const int jj   = orig >> 3;
    const int bn   = (xcd & 3) * 4 + (jj & 3);
    const int bm   = (xcd >> 2) * 32 + (jj >> 2);
    const unsigned short* aB = Ag + ((size_t)bm * 48 * 16 + 4 * wm) * 512 + l * 8;
    const unsigned short* bB = Bg + ((size_t)bn * 48 * 16 + 8 * wn) * 512 + l * 8;

    u16x8 a0[4], a1[4], b0[8], b1[8];
    ALOAD(a0, 0); BLOAD(b0, 0);

    #pragma unroll 1
    for (int i = 0; i < 24; ++i) {
        const int t1 = 2 * i + 1;
        int t2 = 2 * i + 2; if (t2 >= NKT) t2 = 0;
        ALOAD(a1, t1); BLOAD(b1, t1);
        asm volatile("" :: "v"(a0[0]), "v"(a0[1]), "v"(a0[2]), "v"(a0[3]),
                           "v"(b0[0]), "v"(b0[1]), "v"(b0[2]), "v"(b0[3]),
                           "v"(b0[4]), "v"(b0[5]), "v"(b0[6]), "v"(b0[7]));
        ALOAD(a0, t2); BLOAD(b0, t2);
        asm volatile("" :: "v"(a1[0]), "v"(a1[1]), "v"(a1[2]), "v"(a1[3]),
                           "v"(b1[0]), "v"(b1[1]), "v"(b1[2]), "v"(b1[3]),
                           "v"(b1[4]), "v"(b1[5]), "v"(b1[6]), "v"(b1[7]));
    }
    sink[(size_t)(blockIdx.x * 512 + tid)] = (unsigned short)(a0[0][0] ^ b0[0][0]);
}

extern "C" void kernel_launch(void* const* d_in, const int* in_sizes, int n_in,
                              void* d_out, int out_size, void* d_ws, size_t ws_size,
                              hipStream_t stream) {
    const float* x  = (const float*)d_in[0];
    const float* h0 = (const float*)d_in[1];
    const float* c0 = (const float*)d_in[2];
    const float* Uw[4] = {(const float*)d_in[3],  (const float*)d_in[5],
                          (const float*)d_in[7],  (const float*)d_in[9]};
    const float* Ub[4] = {(const float*)d_in[4],  (const float*)d_in[6],
                          (const float*)d_in[8],  (const float*)d_in[10]};
    const float* Ww[4] = {(const float*)d_in[11], (const float*)d_in[13],
                          (const float*)d_in[15], (const float*)d_in[17]};
    const float* Wb[4] = {(const float*)d_in[12], (const float*)d_in[14],
                          (const float*)d_in[16], (const float*)d_in[18]};

    unsigned short* Ag = (unsigned short*)d_ws;                 // 48 MiB
    unsigned short* Bg = Ag + (size_t)B_ROWS * K_TOT;           // 12 MiB
    float* bias        = (float*)(Bg + (size_t)4096 * K_TOT);   // 16 KiB
    float* out         = (float*)d_out;

    cvt_A<<<12288, 256, 0, stream>>>(x, h0, Ag);
    cvt_B<<<3072, 256, 0, stream>>>(Uw[0], Uw[1], Uw[2], Uw[3],
                                    Ww[0], Ww[1], Ww[2], Ww[3], Bg);
    cvt_bias<<<16, 256, 0, stream>>>(Ub[0], Ub[1], Ub[2], Ub[3],
                                     Wb[0], Wb[1], Wb[2], Wb[3], bias);
    lstm_gemm<<<1024, 512, 0, stream>>>(Ag, Bg, bias, c0, out);
    // ---- ablation probes (write only to Ag scratch; Ag is fully rewritten
    //      by cvt_A at the start of every launch, so state never leaks) ----
    probe_mfma<<<1024, 512, 0, stream>>>(Ag, Bg, Ag);
    probe_mem <<<1024, 512, 0, stream>>>(Ag, Bg, Ag);
}

// Round 10
// 285.172 us; speedup vs baseline: 2.0399x; 2.0399x over previous
//
#include <hip/hip_runtime.h>
#include <hip/hip_bf16.h>
#include <stdint.h>

#define B_ROWS 16384
#define D_IN   512
#define H_DIM  1024
#define K_TOT  1536
#define NKT    48          // K-tiles of 32

typedef __attribute__((ext_vector_type(8)))  short bf16x8;
typedef __attribute__((ext_vector_type(4)))  float f32x4;
typedef __attribute__((ext_vector_type(4)))  float float4v;
typedef __attribute__((ext_vector_type(8)))  unsigned short u16x8;

__device__ __forceinline__ unsigned short f2bf(float f) {
    uint32_t u = __float_as_uint(f);
    u = (u + 0x7FFFu + ((u >> 16) & 1u)) >> 16;   // RNE
    return (unsigned short)u;
}

// ---------------------------------------------------------------------------
// Ag fragment-linear for 16x16x32 frags, 128-row block tiles:
//   granule g = ((bm*48 + tile)*8 + chunk)*64 + lane    (16 B each)
//   lane l, elem j: row = bm*128 + chunk*16 + (l&15)
//                   k   = tile*32 + (l>>4)*8 + j
// ---------------------------------------------------------------------------
__global__ void cvt_A(const float* __restrict__ x, const float* __restrict__ h,
                      unsigned short* __restrict__ Ag) {
    int t     = blockIdx.x * blockDim.x + threadIdx.x;
    int lane  = t & 63;
    int chunk = (t >> 6) & 7;
    int rest  = t >> 9;             // bm*48 + tile
    int tile  = rest % 48;
    int bm    = rest / 48;
    int row   = bm * 128 + chunk * 16 + (lane & 15);
    int k     = tile * 32 + (lane >> 4) * 8;
    const float* src = (k < 512) ? (x + (size_t)row * D_IN + k)
                                 : (h + (size_t)row * H_DIM + (k - 512));
    float4v v0 = *(const float4v*)(src);
    float4v v1 = *(const float4v*)(src + 4);
    u16x8 o;
    o[0] = f2bf(v0[0]); o[1] = f2bf(v0[1]); o[2] = f2bf(v0[2]); o[3] = f2bf(v0[3]);
    o[4] = f2bf(v1[0]); o[5] = f2bf(v1[1]); o[6] = f2bf(v1[2]); o[7] = f2bf(v1[3]);
    *(u16x8*)(Ag + (size_t)t * 8) = o;
}

// ---------------------------------------------------------------------------
// Bg fragment-linear, gate-interleaved cols (granularity 16, R1-proven):
//   col c = (h>>4)*64 + gate*16 + (h&15)  -> gate=(c>>4)&3, h=((c>>6)<<4)|(c&15)
//   granule g = ((bn*48 + tile)*8 + chunk)*64 + lane
//   lane l: col = bn*128 + chunk*16 + (l&15); k = tile*32 + (l>>4)*8 + j
// ---------------------------------------------------------------------------
__global__ void cvt_B(const float* __restrict__ Ui, const float* __restrict__ Uf,
                      const float* __restrict__ Uo, const float* __restrict__ Uc,
                      const float* __restrict__ Wi, const float* __restrict__ Wf,
                      const float* __restrict__ Wo, const float* __restrict__ Wc,
                      unsigned short* __restrict__ Bg) {
    int t     = blockIdx.x * blockDim.x + threadIdx.x;
    int lane  = t & 63;
    int chunk = (t >> 6) & 7;
    int rest  = t >> 9;             // bn*48 + tile
    int tile  = rest % 48;
    int bn    = rest / 48;
    int c     = bn * 128 + chunk * 16 + (lane & 15);
    int g     = (c >> 4) & 3;
    int hcol  = ((c >> 6) << 4) | (c & 15);
    int k     = tile * 32 + (lane >> 4) * 8;
    const float* up = (g == 0) ? Ui : (g == 1) ? Uf : (g == 2) ? Uo : Uc;
    const float* wp = (g == 0) ? Wi : (g == 1) ? Wf : (g == 2) ? Wo : Wc;
    u16x8 o;
    if (k < 512) {
        const float* s = up + (size_t)k * H_DIM + hcol;
        #pragma unroll
        for (int i = 0; i < 8; ++i) o[i] = f2bf(s[(size_t)i * H_DIM]);
    } else {
        const float* s = wp + (size_t)(k - 512) * H_DIM + hcol;
        #pragma unroll
        for (int i = 0; i < 8; ++i) o[i] = f2bf(s[(size_t)i * H_DIM]);
    }
    *(u16x8*)(Bg + (size_t)t * 8) = o;
}

__global__ void cvt_bias(const float* __restrict__ Uib, const float* __restrict__ Ufb,
                         const float* __restrict__ Uob, const float* __restrict__ Ucb,
                         const float* __restrict__ Wib, const float* __restrict__ Wfb,
                         const float* __restrict__ Wob, const float* __restrict__ Wcb,
                         float* __restrict__ bias) {
    int t = blockIdx.x * blockDim.x + threadIdx.x;
    int g = t >> 10, h = t & 1023;
    const float* ub = (g == 0) ? Uib : (g == 1) ? Ufb : (g == 2) ? Uob : Ucb;
    const float* wb = (g == 0) ? Wib : (g == 1) ? Wfb : (g == 2) ? Wob : Wcb;
    bias[t] = ub[h] + wb[h];
}

// ---------------------------------------------------------------------------
// 128x128 GEMM block, 256 threads (4 waves 2Mx2N), 16x16x32 MFMA,
// 3-slot LDS ring (48 KB) -> 3 BLOCKS / CU co-resident (12 waves, 3
// independent barrier domains). VGPR forced <= 128 via launch_bounds.
// Per phase t (per wave): 8 ds_read_b128 (4 A + 4 B frags, fragment-linear,
// conflict-free) ; 4 glds staging tile t+2 -> slot (t+2)%3 ; 16 MFMA ;
// vmcnt(4)+barrier. Ring: slot (t+2)%3 = (t-1)%3 freed at t-1's barrier;
// vmcnt(4) leaves only stage(t+2) outstanding => tile t+1 resident.
// ---------------------------------------------------------------------------
__global__ __launch_bounds__(256, 4) void lstm_gemm(
        const unsigned short* __restrict__ Ag, const unsigned short* __restrict__ Bg,
        const float* __restrict__ bias, const float* __restrict__ c_old,
        float* __restrict__ out) {
    __shared__ __align__(1024) char lds[49152];   // 3 slots x 16 KiB

    const int tid = threadIdx.x;
    const int l   = tid & 63;
    const int wv  = tid >> 6;     // 0..3
    const int wm  = wv >> 1;      // 0..1  (64-row slice)
    const int wn  = wv & 1;       // 0..1  (64-col slice)

    // XCD swizzle: bn per XCD (4 values), bm-major with bn interleave
    const int orig = blockIdx.x;              // 4096 blocks
    const int xcd  = orig & 7;
    const int j    = orig >> 3;               // 0..511
    const int bn   = xcd * 4 + (j & 3);       // 0..31
    const int bm   = j >> 2;                  // 0..127

    // staging sources (advance 4096 elems = 8 chunks per tile)
    const unsigned short* aCur = Ag + ((size_t)bm * 48 * 8 + 2 * wv) * 512 + l * 8;
    const unsigned short* bCur = Bg + ((size_t)bn * 48 * 8 + 2 * wv) * 512 + l * 8;

    // in-slot read offsets
    const int aRd = wm * 4096 + l * 16;            // + m*1024
    const int bRd = 8192 + wn * 4096 + l * 16;     // + n*1024

#define GLDS(SRC, DST) __builtin_amdgcn_global_load_lds(                            \
        (const __attribute__((address_space(1))) void*)(SRC),                       \
        (__attribute__((address_space(3))) void*)(DST), 16, 0, 0)

#define STAGE(SLOTBASE) do {                                                        \
    char* _da = (char*)lds + (SLOTBASE) + wv * 2048;                                \
    GLDS(aCur, _da);            GLDS(aCur + 512, _da + 1024);                       \
    GLDS(bCur, _da + 8192);     GLDS(bCur + 512, _da + 8192 + 1024);                \
    aCur += 4096; bCur += 4096;                                                     \
} while (0)

    f32x4 acc[4][4] = {};

#define PHASE(SLOT) do {                                                            \
    const char* _b = (const char*)lds + (SLOT) * 16384;                             \
    bf16x8 aF[4], bF[4];                                                            \
    _Pragma("unroll") for (int m = 0; m < 4; ++m)                                   \
        aF[m] = *(const bf16x8*)(_b + aRd + m * 1024);                              \
    _Pragma("unroll") for (int n = 0; n < 4; ++n)                                   \
        bF[n] = *(const bf16x8*)(_b + bRd + n * 1024);                              \
    STAGE(((((SLOT) + 2) % 3)) * 16384);                                            \
    __builtin_amdgcn_s_setprio(1);                                                  \
    _Pragma("unroll") for (int m = 0; m < 4; ++m)                                   \
        _Pragma("unroll") for (int n = 0; n < 4; ++n)                               \
            acc[m][n] = __builtin_amdgcn_mfma_f32_16x16x32_bf16(                    \
                aF[m], bF[n], acc[m][n], 0, 0, 0);                                  \
    __builtin_amdgcn_s_setprio(0);                                                  \
    asm volatile("s_waitcnt vmcnt(4)\ns_barrier" ::: "memory");                     \
} while (0)

    // ---- prologue: stage tiles 0,1 -> slots 0,1; gate (tile 0 resident) ----
    STAGE(0); STAGE(16384);
    asm volatile("s_waitcnt vmcnt(4)\ns_barrier" ::: "memory");

    // ---- main: phases 0..44 (15 x 3), stages tiles 2..46 ----
    #pragma unroll 1
    for (int i = 0; i < 15; ++i) {
        PHASE(0);
        PHASE(1);
        PHASE(2);
    }
    // phase 45: compute tile 45, stage tile 47 (real)
    PHASE(0);
    // phases 46,47: dummy stages (re-stage tiles 0,1 into retired slots)
    aCur -= (size_t)48 * 4096;  bCur -= (size_t)48 * 4096;
    PHASE(1);
    PHASE(2);
    asm volatile("s_waitcnt vmcnt(0)" ::: "memory");   // drain dummy stagings

    // ---- fused LSTM epilogue (R1-proven mapping): gate = n, in-lane ----
    const int hh  = bn * 32 + wn * 16 + (l & 15);
    const float bi  = bias[hh];
    const float bff = bias[1024 + hh];
    const float bo  = bias[2048 + hh];
    const float bc  = bias[3072 + hh];

    #pragma unroll
    for (int m = 0; m < 4; ++m) {
        const int rb = bm * 128 + wm * 64 + m * 16 + ((l >> 4) * 4);
        #pragma unroll
        for (int jj = 0; jj < 4; ++jj) {
            const int r = rb + jj;
            float iv = acc[m][0][jj] + bi;
            float fv = acc[m][1][jj] + bff;
            float ov = acc[m][2][jj] + bo;
            float gv = acc[m][3][jj] + bc;
            float it = 1.f / (1.f + __expf(-iv));
            float ft = 1.f / (1.f + __expf(-fv));
            float ot = 1.f / (1.f + __expf(-ov));
            float gt = 1.f - 2.f / (1.f + __expf(2.f * gv));
            float co = c_old[(size_t)r * H_DIM + hh];
            float cn = it * gt + ft * co;
            float th = 1.f - 2.f / (1.f + __expf(2.f * cn));
            out[(size_t)r * H_DIM + hh] = ot * th;                          // h_new
            out[(size_t)B_ROWS * H_DIM + (size_t)r * H_DIM + hh] = cn;      // c
        }
    }
#undef PHASE
#undef STAGE
#undef GLDS
}

extern "C" void kernel_launch(void* const* d_in, const int* in_sizes, int n_in,
                              void* d_out, int out_size, void* d_ws, size_t ws_size,
                              hipStream_t stream) {
    const float* x  = (const float*)d_in[0];
    const float* h0 = (const float*)d_in[1];
    const float* c0 = (const float*)d_in[2];
    const float* Uw[4] = {(const float*)d_in[3],  (const float*)d_in[5],
                          (const float*)d_in[7],  (const float*)d_in[9]};
    const float* Ub[4] = {(const float*)d_in[4],  (const float*)d_in[6],
                          (const float*)d_in[8],  (const float*)d_in[10]};
    const float* Ww[4] = {(const float*)d_in[11], (const float*)d_in[13],
                          (const float*)d_in[15], (const float*)d_in[17]};
    const float* Wb[4] = {(const float*)d_in[12], (const float*)d_in[14],
                          (const float*)d_in[16], (const float*)d_in[18]};

    unsigned short* Ag = (unsigned short*)d_ws;                 // 48 MiB
    unsigned short* Bg = Ag + (size_t)B_ROWS * K_TOT;           // 12 MiB
    float* bias        = (float*)(Bg + (size_t)4096 * K_TOT);   // 16 KiB
    float* out         = (float*)d_out;

    cvt_A<<<12288, 256, 0, stream>>>(x, h0, Ag);
    cvt_B<<<3072, 256, 0, stream>>>(Uw[0], Uw[1], Uw[2], Uw[3],
                                    Ww[0], Ww[1], Ww[2], Ww[3], Bg);
    cvt_bias<<<16, 256, 0, stream>>>(Ub[0], Ub[1], Ub[2], Ub[3],
                                     Wb[0], Wb[1], Wb[2], Wb[3], bias);
    lstm_gemm<<<4096, 256, 0, stream>>>(Ag, Bg, bias, c0, out);
}

// Round 11
// 256.230 us; speedup vs baseline: 2.2703x; 1.1129x over previous
//
#include <hip/hip_runtime.h>
#include <hip/hip_bf16.h>
#include <stdint.h>

#define B_ROWS 16384
#define D_IN   512
#define H_DIM  1024
#define K_TOT  1536
#define NT64   24          // K-tiles of 64

typedef __attribute__((ext_vector_type(8)))  short bf16x8;
typedef __attribute__((ext_vector_type(4)))  float f32x4;
typedef __attribute__((ext_vector_type(4)))  float float4v;
typedef __attribute__((ext_vector_type(8)))  unsigned short u16x8;

__device__ __forceinline__ unsigned short f2bf(float f) {
    uint32_t u = __float_as_uint(f);
    u = (u + 0x7FFFu + ((u >> 16) & 1u)) >> 16;   // RNE
    return (unsigned short)u;
}

// ---------------------------------------------------------------------------
// Ag fragment-linear, 256-row tiles, BK=64 split in k-halves:
//   granule g = (((bm*24 + T)*2 + kh)*16 + chunk)*64 + lane   (16 B)
//   lane l: row = bm*256 + chunk*16 + (l&15) ; k = T*64 + kh*32 + (l>>4)*8 + j
// ---------------------------------------------------------------------------
__global__ void cvt_A(const float* __restrict__ x, const float* __restrict__ h,
                      unsigned short* __restrict__ Ag) {
    int t     = blockIdx.x * blockDim.x + threadIdx.x;
    int lane  = t & 63;
    int chunk = (t >> 6) & 15;
    int kh    = (t >> 10) & 1;
    int rest  = t >> 11;            // bm*24 + T
    int T     = rest % 24;
    int bm    = rest / 24;
    int row   = bm * 256 + chunk * 16 + (lane & 15);
    int k     = T * 64 + kh * 32 + (lane >> 4) * 8;
    const float* src = (k < 512) ? (x + (size_t)row * D_IN + k)
                                 : (h + (size_t)row * H_DIM + (k - 512));
    float4v v0 = *(const float4v*)(src);
    float4v v1 = *(const float4v*)(src + 4);
    u16x8 o;
    o[0] = f2bf(v0[0]); o[1] = f2bf(v0[1]); o[2] = f2bf(v0[2]); o[3] = f2bf(v0[3]);
    o[4] = f2bf(v1[0]); o[5] = f2bf(v1[1]); o[6] = f2bf(v1[2]); o[7] = f2bf(v1[3]);
    *(u16x8*)(Ag + (size_t)t * 8) = o;
}

// ---------------------------------------------------------------------------
// Bg fragment-linear, gate-interleaved cols (granularity 16, R1-proven):
//   col c = (h>>4)*64 + gate*16 + (h&15)
//   granule g = (((bn*24 + T)*2 + kh)*16 + chunk)*64 + lane
//   lane l: c = bn*256 + chunk*16 + (l&15) ; k = T*64 + kh*32 + (l>>4)*8 + j
// ---------------------------------------------------------------------------
__global__ void cvt_B(const float* __restrict__ Ui, const float* __restrict__ Uf,
                      const float* __restrict__ Uo, const float* __restrict__ Uc,
                      const float* __restrict__ Wi, const float* __restrict__ Wf,
                      const float* __restrict__ Wo, const float* __restrict__ Wc,
                      unsigned short* __restrict__ Bg) {
    int t     = blockIdx.x * blockDim.x + threadIdx.x;
    int lane  = t & 63;
    int chunk = (t >> 6) & 15;
    int kh    = (t >> 10) & 1;
    int rest  = t >> 11;            // bn*24 + T
    int T     = rest % 24;
    int bn    = rest / 24;
    int c     = bn * 256 + chunk * 16 + (lane & 15);
    int g     = (c >> 4) & 3;
    int hcol  = ((c >> 6) << 4) | (c & 15);
    int k     = T * 64 + kh * 32 + (lane >> 4) * 8;
    const float* up = (g == 0) ? Ui : (g == 1) ? Uf : (g == 2) ? Uo : Uc;
    const float* wp = (g == 0) ? Wi : (g == 1) ? Wf : (g == 2) ? Wo : Wc;
    u16x8 o;
    if (k < 512) {
        const float* s = up + (size_t)k * H_DIM + hcol;
        #pragma unroll
        for (int i = 0; i < 8; ++i) o[i] = f2bf(s[(size_t)i * H_DIM]);
    } else {
        const float* s = wp + (size_t)(k - 512) * H_DIM + hcol;
        #pragma unroll
        for (int i = 0; i < 8; ++i) o[i] = f2bf(s[(size_t)i * H_DIM]);
    }
    *(u16x8*)(Bg + (size_t)t * 8) = o;
}

__global__ void cvt_bias(const float* __restrict__ Uib, const float* __restrict__ Ufb,
                         const float* __restrict__ Uob, const float* __restrict__ Ucb,
                         const float* __restrict__ Wib, const float* __restrict__ Wfb,
                         const float* __restrict__ Wob, const float* __restrict__ Wcb,
                         float* __restrict__ bias) {
    int t = blockIdx.x * blockDim.x + threadIdx.x;
    int g = t >> 10, h = t & 1023;
    const float* ub = (g == 0) ? Uib : (g == 1) ? Ufb : (g == 2) ? Uob : Ucb;
    const float* wb = (g == 0) ? Wib : (g == 1) ? Wfb : (g == 2) ? Wob : Wcb;
    bias[t] = ub[h] + wb[h];
}

// ---------------------------------------------------------------------------
// m201-faithful 256x256 8-phase GEMM, BK=64, 512 thr (8 waves 2Mx4N),
// 16x16x32 MFMA, per-wave 128x64 (acc[8][4]).
// Phases = (K-half x M-half) per tile; q0 reads 4A+4B, q1 reads 4A (B in regs).
// LDS 128 KB: buf(2) x mat(2) x khalf(2) x 16 KB, fragment-linear (0 conflicts).
// Region lifetimes (reads): buf0.A.k0:ph1-2, B.k0:ph1, A.k1:ph3-4, B.k1:ph3,
//   buf1.A.k0:ph5-6, B.k0:ph5, A.k1:ph7-8, B.k1:ph7.
// Stages (1 region/phase, after the target's last-read barrier):
//   ph1:A(t1).k1->b1  ph2:B(t1).k1->b1  ph3:A(t2).k0->b0  ph4:B(t2).k0->b0
//   ph5:A(t2).k1->b0  ph6:B(t2).k1->b0  ph7:A(t3).k0->b1  ph8:B(t3).k0->b1
// Gates: vmcnt(4) at ph4 and ph8 ONLY (retires everything except the last 2
// regions; every first-read is >=1 gate after its stage). Never vmcnt(0).
// Phase body: {reads; stage; barrier; lgkmcnt(0); sched_barrier; setprio(1);
// 16 MFMA; setprio(0); barrier(+gate)}.
// ---------------------------------------------------------------------------
__global__ __launch_bounds__(512) void lstm_gemm(
        const unsigned short* __restrict__ Ag, const unsigned short* __restrict__ Bg,
        const float* __restrict__ bias, const float* __restrict__ c_old,
        float* __restrict__ out) {
    __shared__ __align__(1024) char lds[131072];

    const int tid = threadIdx.x;
    const int l   = tid & 63;
    const int wv  = tid >> 6;
    const int wm  = wv >> 2;      // 0..1  (128-row slice)
    const int wn  = wv & 3;       // 0..3  (64-col slice)

    // XCD swizzle: per XCD 8bm x 4bn
    const int orig = blockIdx.x;              // 1024 blocks
    const int xcd  = orig & 7;
    const int jj   = orig >> 3;
    const int bn   = (xcd & 3) * 4 + (jj & 3);     // 0..15
    const int bm   = (xcd >> 2) * 32 + (jj >> 2);  // 0..63

    // staging sources: region (T,kh) at +((T*2+kh)*8192) elems; thread granule
    const unsigned short* aSrc = Ag + (size_t)bm * 24 * 16384 + tid * 8;
    const unsigned short* bSrc = Bg + (size_t)bn * 24 * 16384 + tid * 8;

    // LDS read lane offsets
    const int aRd = wm * 8192 + l * 16;     // + (q*4+m)*1024
    const int bRd = wn * 4096 + l * 16;     // + n*1024

#define GLDS(SRC, DST) __builtin_amdgcn_global_load_lds(                            \
        (const __attribute__((address_space(1))) void*)(SRC),                       \
        (__attribute__((address_space(3))) void*)(DST), 16, 0, 0)

#define STAGE(MAT, T, KH, BUF) do {                                                 \
    const unsigned short* _s = ((MAT) ? bSrc : aSrc) + (size_t)((T) * 2 + (KH)) * 8192; \
    char* _d = (char*)lds + (BUF) * 65536 + (MAT) * 32768 + (KH) * 16384 + wv * 1024;   \
    GLDS(_s, _d);  GLDS(_s + 4096, _d + 8192);                                      \
} while (0)

    f32x4 acc[8][4] = {};
    bf16x8 bPers[4];

#define PHASE(BUF, KH, Q, RB, SM, ST, SKH, SBUF, GATE) do {                         \
    const char* _Ab = (const char*)lds + (BUF) * 65536 + (KH) * 16384 + aRd;        \
    bf16x8 aF[4];                                                                   \
    _Pragma("unroll") for (int m = 0; m < 4; ++m)                                   \
        aF[m] = *(const bf16x8*)(_Ab + ((Q) * 4 + m) * 1024);                       \
    if (RB) {                                                                       \
        const char* _Bb = (const char*)lds + (BUF) * 65536 + 32768 + (KH) * 16384 + bRd; \
        _Pragma("unroll") for (int n = 0; n < 4; ++n)                               \
            bPers[n] = *(const bf16x8*)(_Bb + n * 1024);                            \
    }                                                                               \
    STAGE(SM, ST, SKH, SBUF);                                                       \
    __builtin_amdgcn_s_barrier();                                                   \
    asm volatile("s_waitcnt lgkmcnt(0)" ::: "memory");                              \
    __builtin_amdgcn_sched_barrier(0);                                              \
    __builtin_amdgcn_s_setprio(1);                                                  \
    _Pragma("unroll") for (int m = 0; m < 4; ++m)                                   \
        _Pragma("unroll") for (int n = 0; n < 4; ++n)                               \
            acc[(Q) * 4 + m][n] = __builtin_amdgcn_mfma_f32_16x16x32_bf16(          \
                aF[m], bPers[n], acc[(Q) * 4 + m][n], 0, 0, 0);                     \
    __builtin_amdgcn_s_setprio(0);                                                  \
    if (GATE) { asm volatile("s_waitcnt vmcnt(4)\ns_barrier" ::: "memory"); }       \
    else      { asm volatile("s_barrier" ::: "memory"); }                           \
} while (0)

    // ---- prologue: T0 fully + T1.k0 (12 loads); vmcnt(4) retires T0 ----
    STAGE(0, 0, 0, 0); STAGE(1, 0, 0, 0);
    STAGE(0, 0, 1, 0); STAGE(1, 0, 1, 0);
    STAGE(0, 1, 0, 1); STAGE(1, 1, 0, 1);
    asm volatile("s_waitcnt vmcnt(4)\ns_barrier" ::: "memory");

    // ---- main loop: 12 iterations, tiles 2i (buf0) and 2i+1 (buf1) ----
    #pragma unroll 1
    for (int i = 0; i < 12; ++i) {
        const int t1 = 2 * i + 1;
        int t2 = 2 * i + 2; if (t2 >= NT64) t2 -= NT64;   // wrap: staged, never read
        int t3 = 2 * i + 3; if (t3 >= NT64) t3 -= NT64;
        PHASE(0, 0, 0, 1,  0, t1, 1, 1,  0);   // T0.k0.q0 ; stage A(t1).k1->b1
        PHASE(0, 0, 1, 0,  1, t1, 1, 1,  0);   // T0.k0.q1 ; stage B(t1).k1->b1
        PHASE(0, 1, 0, 1,  0, t2, 0, 0,  0);   // T0.k1.q0 ; stage A(t2).k0->b0
        PHASE(0, 1, 1, 0,  1, t2, 0, 0,  1);   // T0.k1.q1 ; stage B(t2).k0 ; GATE
        PHASE(1, 0, 0, 1,  0, t2, 1, 0,  0);   // T1.k0.q0 ; stage A(t2).k1->b0
        PHASE(1, 0, 1, 0,  1, t2, 1, 0,  0);   // T1.k0.q1 ; stage B(t2).k1->b0
        PHASE(1, 1, 0, 1,  0, t3, 0, 1,  0);   // T1.k1.q0 ; stage A(t3).k0->b1
        PHASE(1, 1, 1, 0,  1, t3, 0, 1,  1);   // T1.k1.q1 ; stage B(t3).k0 ; GATE
    }
    asm volatile("s_waitcnt vmcnt(0)" ::: "memory");   // drain wrapped stagings

    // ---- fused LSTM epilogue: gate = n (in-lane), hh = (bn*4+wn)*16 + col ----
    const int hh  = (bn * 4 + wn) * 16 + (l & 15);
    const float bi  = bias[hh];
    const float bff = bias[1024 + hh];
    const float bo  = bias[2048 + hh];
    const float bc  = bias[3072 + hh];

    #pragma unroll
    for (int a = 0; a < 8; ++a) {
        const int rb = bm * 256 + wm * 128 + (a >> 2) * 64 + (a & 3) * 16 + ((l >> 4) * 4);
        #pragma unroll
        for (int j = 0; j < 4; ++j) {
            const int r = rb + j;
            float iv = acc[a][0][j] + bi;
            float fv = acc[a][1][j] + bff;
            float ov = acc[a][2][j] + bo;
            float gv = acc[a][3][j] + bc;
            float it = 1.f / (1.f + __expf(-iv));
            float ft = 1.f / (1.f + __expf(-fv));
            float ot = 1.f / (1.f + __expf(-ov));
            float gt = 1.f - 2.f / (1.f + __expf(2.f * gv));
            float co = c_old[(size_t)r * H_DIM + hh];
            float cn = it * gt + ft * co;
            float th = 1.f - 2.f / (1.f + __expf(2.f * cn));
            out[(size_t)r * H_DIM + hh] = ot * th;                          // h_new
            out[(size_t)B_ROWS * H_DIM + (size_t)r * H_DIM + hh] = cn;      // c
        }
    }
#undef PHASE
#undef STAGE
#undef GLDS
}

extern "C" void kernel_launch(void* const* d_in, const int* in_sizes, int n_in,
                              void* d_out, int out_size, void* d_ws, size_t ws_size,
                              hipStream_t stream) {
    const float* x  = (const float*)d_in[0];
    const float* h0 = (const float*)d_in[1];
    const float* c0 = (const float*)d_in[2];
    const float* Uw[4] = {(const float*)d_in[3],  (const float*)d_in[5],
                          (const float*)d_in[7],  (const float*)d_in[9]};
    const float* Ub[4] = {(const float*)d_in[4],  (const float*)d_in[6],
                          (const float*)d_in[8],  (const float*)d_in[10]};
    const float* Ww[4] = {(const float*)d_in[11], (const float*)d_in[13],
                          (const float*)d_in[15], (const float*)d_in[17]};
    const float* Wb[4] = {(const float*)d_in[12], (const float*)d_in[14],
                          (const float*)d_in[16], (const float*)d_in[18]};

    unsigned short* Ag = (unsigned short*)d_ws;                 // 48 MiB
    unsigned short* Bg = Ag + (size_t)B_ROWS * K_TOT;           // 12 MiB
    float* bias        = (float*)(Bg + (size_t)4096 * K_TOT);   // 16 KiB
    float* out         = (float*)d_out;

    cvt_A<<<12288, 256, 0, stream>>>(x, h0, Ag);
    cvt_B<<<3072, 256, 0, stream>>>(Uw[0], Uw[1], Uw[2], Uw[3],
                                    Ww[0], Ww[1], Ww[2], Ww[3], Bg);
    cvt_bias<<<16, 256, 0, stream>>>(Ub[0], Ub[1], Ub[2], Ub[3],
                                     Wb[0], Wb[1], Wb[2], Wb[3], bias);
    lstm_gemm<<<1024, 512, 0, stream>>>(Ag, Bg, bias, c0, out);
}